// Round 4
// baseline (174.906 us; speedup 1.0000x reference)
//
#include <hip/hip_runtime.h>

#define TT 2048
#define NB 16
#define FD 128
#define ALPHA 0.2f

typedef __attribute__((ext_vector_type(8))) short short8;
typedef __attribute__((ext_vector_type(4))) float f32x4;

static __device__ __forceinline__ unsigned short f2bf(float f) {
    unsigned u = __float_as_uint(f);
    u += 0x7FFF + ((u >> 16) & 1);          // round-to-nearest-even
    return (unsigned short)(u >> 16);
}
static __device__ __forceinline__ float bf2f(unsigned short s) {
    return __uint_as_float(((unsigned)s) << 16);
}

// Kernel 0: WT[f][k] = bf16(W[k][f])  (128x128, tiny)
__global__ __launch_bounds__(256) void k_wt(const float* __restrict__ W,
                                            unsigned short* __restrict__ WT)
{
    int fid = blockIdx.x * 256 + threadIdx.x;   // 4096 float4s
    int k = fid >> 5;
    int f = (fid & 31) << 2;
    float4 w4 = *reinterpret_cast<const float4*>(W + k * FD + f);
    WT[(f + 0) * FD + k] = f2bf(w4.x);
    WT[(f + 1) * FD + k] = f2bf(w4.y);
    WT[(f + 2) * FD + k] = f2bf(w4.z);
    WT[(f + 3) * FD + k] = f2bf(w4.w);
}

// Kernel 1: h = x@W (bf16 MFMA, WT from L2), write hT[b][f][t] bf16,
//           s1 = h@a1, s2 = h@a2 (fp32)
__global__ __launch_bounds__(256) void k_h(const float* __restrict__ x,
                                           const unsigned short* __restrict__ WT,
                                           const float* __restrict__ a,
                                           unsigned short* __restrict__ hT,
                                           float* __restrict__ s1,
                                           float* __restrict__ s2)
{
    __shared__ unsigned short hs[128][72];   // h-tile transpose staging

    const int tid = threadIdx.x;
    const int b  = blockIdx.x >> 5;
    const int t0 = (blockIdx.x & 31) << 6;
    const int w = tid >> 6, l = tid & 63, g = l >> 4, r15 = l & 15;

    const float* xrow = x + ((size_t)(b * TT + t0 + w * 16 + r15)) * FD;

    f32x4 acc[8] = {};

    #pragma unroll
    for (int m = 0; m < 4; ++m) {
        const int koff = m * 32 + g * 8;
        float4 xa = *reinterpret_cast<const float4*>(xrow + koff);
        float4 xb = *reinterpret_cast<const float4*>(xrow + koff + 4);
        short8 af;
        af[0] = (short)f2bf(xa.x); af[1] = (short)f2bf(xa.y);
        af[2] = (short)f2bf(xa.z); af[3] = (short)f2bf(xa.w);
        af[4] = (short)f2bf(xb.x); af[5] = (short)f2bf(xb.y);
        af[6] = (short)f2bf(xb.z); af[7] = (short)f2bf(xb.w);
        #pragma unroll
        for (int n = 0; n < 8; ++n) {
            short8 bfr = *reinterpret_cast<const short8*>(WT + (n * 16 + r15) * FD + koff);
            acc[n] = __builtin_amdgcn_mfma_f32_16x16x32_bf16(af, bfr, acc[n], 0, 0, 0);
        }
    }

    // s1/s2 from fp32 accumulators: lane holds h[t0+w*16+4g+r][16n+r15]
    float p1[4] = {0.f, 0.f, 0.f, 0.f}, p2[4] = {0.f, 0.f, 0.f, 0.f};
    #pragma unroll
    for (int n = 0; n < 8; ++n) {
        float a1v = a[n * 16 + r15];
        float a2v = a[FD + n * 16 + r15];
        #pragma unroll
        for (int r = 0; r < 4; ++r) {
            p1[r] += acc[n][r] * a1v;
            p2[r] += acc[n][r] * a2v;
        }
    }
    #pragma unroll
    for (int r = 0; r < 4; ++r) {
        #pragma unroll
        for (int off = 8; off >= 1; off >>= 1) {
            p1[r] += __shfl_xor(p1[r], off);
            p2[r] += __shfl_xor(p2[r], off);
        }
    }
    if (r15 == 0) {
        const int trow = t0 + w * 16 + g * 4;
        #pragma unroll
        for (int r = 0; r < 4; ++r) {
            s1[b * TT + trow + r] = p1[r];
            s2[b * TT + trow + r] = p2[r];
        }
    }

    // transpose h tile through LDS, write hT[b][f][t] coalesced
    #pragma unroll
    for (int n = 0; n < 8; ++n)
        #pragma unroll
        for (int r = 0; r < 4; ++r)
            hs[n * 16 + r15][w * 16 + g * 4 + r] = f2bf(acc[n][r]);
    __syncthreads();

    for (int i = tid; i < 1024; i += 256) {
        int f = i >> 3, c = i & 7;
        short8 v = *reinterpret_cast<const short8*>(&hs[f][c * 8]);
        *reinterpret_cast<short8*>(hT + ((size_t)(b * FD + f)) * TT + t0 + c * 8) = v;
    }
}

// Kernel 2: producer/consumer fused mask+softmax+PV.
// Block = 16 i-rows x full j, 4 waves split f (32 each). 2048 blocks ->
// 8 blocks/CU -> 100% occupancy. Per 128-j tile: producer (all threads)
// computes p bf16 -> LDS (double-buffered, adj register-prefetched one tile
// ahead); consumer MFMAs vs L2-resident hT. One raw s_barrier per tile
// (lgkmcnt drain only - adj loads stay in flight across the barrier).
__global__ __launch_bounds__(256, 8) void k_att(const int* __restrict__ adj,
                                                const unsigned short* __restrict__ hT,
                                                const float* __restrict__ s1,
                                                const float* __restrict__ s2,
                                                float* __restrict__ out)
{
    __shared__ __align__(16) unsigned short pbuf[2][16][136]; // 17x16B row stride
    __shared__ float dsum[16];

    const int tid = threadIdx.x;
    // bijective XCD swizzle: 2048 blocks = 8 XCDs x 256 contiguous
    const int wg = (blockIdx.x & 7) * 256 + (blockIdx.x >> 3);
    const int b  = wg >> 7;
    const int i0 = (wg & 127) << 4;
    const int w = tid >> 6, l = tid & 63, g = l >> 4, r15 = l & 15;

    // producer mapping: thread -> (row pr in 0..15, 8-col group cg in 0..15)
    const int pr = tid >> 4;
    const int cg = tid & 15;
    const int* adjp = adj + ((size_t)(b * TT + i0 + pr)) * TT + cg * 8;
    const float s1v = s1[b * TT + i0 + pr];
    const float* s2p = s2 + b * TT + cg * 8;
    unsigned short* prow = &pbuf[0][pr][cg * 8];

    // consumer mapping: wave w owns f-slice [w*32, w*32+32)
    const int f0 = w * 32;
    const unsigned short* hB0 = hT + (size_t)b * FD * TT + (size_t)(f0 + r15) * TT;
    const unsigned short* hB1 = hB0 + (size_t)(16 * TT);

    f32x4 acc0 = {}, acc1 = {};
    float rsum = 0.f;

    int4 arA[2], arB[2];
    arA[0] = *reinterpret_cast<const int4*>(adjp);
    arA[1] = *reinterpret_cast<const int4*>(adjp + 4);

    auto body = [&](int t, int4 (&cur)[2], int4 (&nxt)[2], const int bsel) {
        const int j0 = t * 128;
        if (t < 15) {                       // prefetch next adj tile
            nxt[0] = *reinterpret_cast<const int4*>(adjp + j0 + 128);
            nxt[1] = *reinterpret_cast<const int4*>(adjp + j0 + 132);
        }
        float4 s2a = *reinterpret_cast<const float4*>(s2p + j0);
        float4 s2b = *reinterpret_cast<const float4*>(s2p + j0 + 4);
        short8 v0;
        const int* cai = (const int*)cur;
        float csf[8] = {s2a.x, s2a.y, s2a.z, s2a.w, s2b.x, s2b.y, s2b.z, s2b.w};
        #pragma unroll
        for (int e = 0; e < 8; ++e) {
            float s = s1v + csf[e];
            s = fmaxf(s, ALPHA * s);                 // leaky_relu
            float p = cai[e] ? __expf(s) : 0.f;      // mask
            unsigned short u = f2bf(p);
            rsum += bf2f(u);                         // denom from rounded p
            v0[e] = (short)u;
        }
        *reinterpret_cast<short8*>(prow + bsel * (16 * 136)) = v0;
        asm volatile("s_waitcnt lgkmcnt(0)" ::: "memory"); // LDS writes visible
        __builtin_amdgcn_s_barrier();                      // no vmcnt drain
        asm volatile("" ::: "memory");
        const unsigned short* pb = &pbuf[bsel][0][0];
        #pragma unroll
        for (int kk = 0; kk < 4; ++kk) {
            short8 A0 = *reinterpret_cast<const short8*>(pb + r15 * 136 + kk * 32 + g * 8);
            short8 B0 = *reinterpret_cast<const short8*>(hB0 + j0 + kk * 32 + g * 8);
            short8 B1 = *reinterpret_cast<const short8*>(hB1 + j0 + kk * 32 + g * 8);
            acc0 = __builtin_amdgcn_mfma_f32_16x16x32_bf16(A0, B0, acc0, 0, 0, 0);
            acc1 = __builtin_amdgcn_mfma_f32_16x16x32_bf16(A0, B1, acc1, 0, 0, 0);
        }
    };

    for (int tt = 0; tt < 8; ++tt) {
        body(2 * tt,     arA, arB, 0);
        body(2 * tt + 1, arB, arA, 1);
    }

    // row-sum reduce: 16 threads per row, all within one wave
    rsum += __shfl_xor(rsum, 1);
    rsum += __shfl_xor(rsum, 2);
    rsum += __shfl_xor(rsum, 4);
    rsum += __shfl_xor(rsum, 8);
    if ((tid & 15) == 0) dsum[pr] = rsum;
    __syncthreads();

    float rinv[4];
    #pragma unroll
    for (int r = 0; r < 4; ++r) rinv[r] = 1.0f / dsum[g * 4 + r];

    const size_t obase = ((size_t)(b * TT + i0)) * FD + f0 + r15;
    #pragma unroll
    for (int r = 0; r < 4; ++r) {
        float* o = out + obase + (size_t)(g * 4 + r) * FD;
        o[0]  = acc0[r] * rinv[r];
        o[16] = acc1[r] * rinv[r];
    }
}

extern "C" void kernel_launch(void* const* d_in, const int* in_sizes, int n_in,
                              void* d_out, int out_size, void* d_ws, size_t ws_size,
                              hipStream_t stream)
{
    const float* x  = (const float*)d_in[0];
    const int* adj  = (const int*)d_in[1];
    const float* W  = (const float*)d_in[2];
    const float* a  = (const float*)d_in[3];
    float* out = (float*)d_out;

    unsigned short* hT = (unsigned short*)d_ws;                       // 8 MB bf16
    float* s1 = (float*)((char*)d_ws + (size_t)NB * FD * TT * 2);
    float* s2 = s1 + NB * TT;
    unsigned short* WT = (unsigned short*)(s2 + NB * TT);             // 32 KB bf16

    k_wt <<<16, 256, 0, stream>>>(W, WT);
    k_h  <<<NB * (TT / 64), 256, 0, stream>>>(x, WT, a, hT, s1, s2);
    k_att<<<NB * (TT / 16), 256, 0, stream>>>(adj, hT, s1, s2, out);
}